// Round 9
// baseline (875.477 us; speedup 1.0000x reference)
//
#include <hip/hip_runtime.h>
#include <math.h>

#define L_SEQ 2048
#define B_SZ 16
#define DIN 64
#define H_SZ 512
#define N_ST 64
#define N_LAYERS 4
#define Q_CHUNK 64
#define N_CHUNKS (L_SEQ / Q_CHUNK)   // 32
#define GSZ 4                         // chunks per pipeline group
#define N_GROUPS (N_CHUNKS / GSZ)     // 8
#define UPAD 2056                     // U_all row stride in f16 (16B-aligned)
#define NTHR 768                      // 12 waves: 4 scan + 8 out
#define BH 8                          // batch rows per block (B-split)

typedef _Float16 f16;
typedef _Float16 f16x8 __attribute__((ext_vector_type(8)));
typedef _Float16 f16x4 __attribute__((ext_vector_type(4)));
typedef float    f32x4 __attribute__((ext_vector_type(4)));

struct cx { float r, i; };
__device__ __forceinline__ cx cmul(cx a, cx b) {
    return { a.r * b.r - a.i * b.i, a.r * b.i + a.i * b.r };
}

// LDS-only barrier (global loads/stores may stay in flight across it)
__device__ __forceinline__ void barrier_lgkm() {
    asm volatile("s_waitcnt lgkmcnt(0)\n\ts_barrier" ::: "memory");
}

// ---------- encoder (MFMA): out[h][b][l] = f16( sum_k x[l][b][k] W[k][h] + bias[h] ) ----------
__global__ __launch_bounds__(256, 4)
void encoder_mfma_kernel(const float* __restrict__ x, const float* __restrict__ W,
                         const float* __restrict__ bias, f16* __restrict__ out)
{
    __shared__ f16   x_sh[64][72];    // [l][k]
    __shared__ f16   w_t[64][72];     // [h][k]
    __shared__ float out_sh[64][68];
    __shared__ float b_sh[64];
    const int tid = threadIdx.x;
    const int bid = blockIdx.x;
    const int bb  = bid & 15;
    const int lt  = (bid >> 4) & 31;
    const int ht  = bid >> 9;
    const int l0 = lt * 64, h0 = ht * 64;

#pragma unroll
    for (int i = 0; i < 4; ++i) {
        int e  = tid + i * 256;            // 0..1023
        int r  = e >> 4;                   // 0..63 (l for x, k for W)
        int c4 = (e & 15) * 4;             // 0..60
        float4 xv = *(const float4*)&x[((size_t)(l0 + r) * B_SZ + bb) * DIN + c4];
        f16x4 xo; xo[0] = (f16)xv.x; xo[1] = (f16)xv.y; xo[2] = (f16)xv.z; xo[3] = (f16)xv.w;
        *(f16x4*)&x_sh[r][c4] = xo;        // [l][k]
        float4 wv = *(const float4*)&W[(size_t)r * H_SZ + h0 + c4];
        w_t[c4 + 0][r] = (f16)wv.x;        // [h][k] (transposed scatter)
        w_t[c4 + 1][r] = (f16)wv.y;
        w_t[c4 + 2][r] = (f16)wv.z;
        w_t[c4 + 3][r] = (f16)wv.w;
    }
    if (tid < 64) b_sh[tid] = bias[h0 + tid];
    __syncthreads();

    const int wave = tid >> 6;
    const int lane = tid & 63;
    const int frow = lane & 15;
    const int fk   = (lane >> 4) * 8;
    const int m0   = wave * 16;            // h strip per wave

    f16x8 a0 = *(const f16x8*)&w_t[m0 + frow][fk];
    f16x8 a1 = *(const f16x8*)&w_t[m0 + frow][fk + 32];
    float bv[4];
#pragma unroll
    for (int j = 0; j < 4; ++j) bv[j] = b_sh[m0 + (lane >> 4) * 4 + j];

#pragma unroll
    for (int nt = 0; nt < 4; ++nt) {       // l tiles
        f16x8 b0 = *(const f16x8*)&x_sh[nt * 16 + frow][fk];
        f16x8 b1 = *(const f16x8*)&x_sh[nt * 16 + frow][fk + 32];
        f32x4 acc = {0.f, 0.f, 0.f, 0.f};
        acc = __builtin_amdgcn_mfma_f32_16x16x32_f16(a0, b0, acc, 0, 0, 0);
        acc = __builtin_amdgcn_mfma_f32_16x16x32_f16(a1, b1, acc, 0, 0, 0);
#pragma unroll
        for (int j = 0; j < 4; ++j)
            out_sh[m0 + (lane >> 4) * 4 + j][nt * 16 + frow] = acc[j] + bv[j];
    }
    __syncthreads();

#pragma unroll
    for (int i = 0; i < 4; ++i) {
        int row = (tid >> 4) + i * 16;     // h row
        int c4  = (tid & 15) * 4;          // l col
        f32x4 v = *(const f32x4*)&out_sh[row][c4];
        f16x4 o;
#pragma unroll
        for (int k = 0; k < 4; ++k) o[k] = (f16)v[k];
        *(f16x4*)&out[((size_t)(h0 + row) * B_SZ + bb) * L_SEQ + l0 + c4] = o;
    }
}

// ---------- fused 4-layer S4D, B-split: one block per (h, 8-batch half) ----------
// LDS 78.5 KB -> 2 blocks/CU (the point of this round: barrier-idle of one
// block is filled by the other). E-operand fragments are built per-lane in
// REGISTERS (binary-exp jump + 8-step walk), so A_lds holds only the Toeplitz.
// MFMA row index b uses frow&7 (rows 8-15 = broadcast duplicates, finite,
// column-contained); every store is predicated frow<8.
// Per-layer prologue (3 intervals, all 12 waves):
//   A: per-lane params; G chains 6-way split (role=wave&1, seg=wave>>1,
//      11 steps, seg-jump via (dA^11)^seg); wave0 writes dBv; w at j=64;
//      scan waves also build E-frags for n=16*wave+frow.
//   B: K[d] = G_ext[d].dBv (512 thr).   C: Toeplitz expansion (+D diagonal).
// Main loop: round-7 body (1 barrier/group-iter), scan idle at g=8,9.
__global__ __launch_bounds__(NTHR, 6)
void s4d_fused_kernel(f16* __restrict__ u_io,          // [H][B][L] f16: encoder out; final y in place
                      const float* __restrict__ log_dt, const float* __restrict__ log_A_re,
                      const float* __restrict__ A_im, const float* __restrict__ C_re,
                      const float* __restrict__ C_im, const float* __restrict__ Dskip,
                      float* __restrict__ st_re, float* __restrict__ st_im)
{
    __shared__ f16   A_lds[64][72];          //  9216 B: Toeplitz(K)+D.I
    __shared__ f16   G_lds[65][136];         // 17680 B: G_ext[j][n2], j=0..64
    __shared__ f16   U_all[BH][UPAD];        // 32896 B: per-(h,bh) sequence, in place
    __shared__ f16   S_buf[2][GSZ][BH][136]; // 17408 B: S_pre per chunk of group
    __shared__ float dBv_sh[128];            //   512 B
    __shared__ float K_sh[64];               //   256 B
    __shared__ float w_sh[64][2];            //   512 B
    // total 78480 B -> 2 blocks/CU

    const int tid  = threadIdx.x;
    const int wave = tid >> 6;
    const int lane = tid & 63;
    const int h    = blockIdx.x >> 1;
    const int bh   = blockIdx.x & 1;         // batch half
    const int frow = lane & 15;
    const int fq   = lane >> 4;
    const int fk   = fq * 8;
    const int fr8  = frow & 7;               // MFMA b-row within 8 (rows 8-15 duplicate)

    // ---- stage this block's 8 batch rows into LDS ----
    {
        const f16* ub = u_io + ((size_t)h * B_SZ + bh * BH) * L_SEQ;
        for (int u0 = tid; u0 < BH * 256; u0 += NTHR) {
            int b = u0 >> 8, cidx = (u0 & 255) * 8;
            *(f16x8*)&U_all[b][cidx] = *(const f16x8*)&ub[(size_t)b * L_SEQ + cidx];
        }
    }
    f16* yb = u_io + ((size_t)h * B_SZ + bh * BH) * L_SEQ;   // final-layer f16 output

    for (int layer = 0; layer < N_LAYERS; ++layer) {
        const int ph = layer * H_SZ + h;
        const int pn = ph * N_ST + lane;
        const float Dv = Dskip[ph];          // folded into Toeplitz diagonal

        // fragments (persist through the layer)
        f16x8 aRe0, aRe1, aIm0, aIm1;        // scan (register-built E)
        f16x8 aT0[2], aT1[2], aG[2][4];      // out
        float wr4[4], wi4[4];
        float s_r[4] = {0.f,0.f,0.f,0.f}, s_i[4] = {0.f,0.f,0.f,0.f};

        // ---- interval A: G chains (6-way) + dBv + w + per-lane E-frag build ----
        {
            float dt   = expf(log_dt[ph]);
            float Are  = -expf(log_A_re[pn]);
            float Aim  = A_im[pn];
            float mg   = expf(dt * Are);
            float phs  = dt * Aim;
            cx dA1 = { mg * cosf(phs), mg * sinf(phs) };
            float invd = 1.0f / (Are * Are + Aim * Aim);
            float nr   = dA1.r - 1.0f;
            float dBr  = (nr * Are + dA1.i * Aim) * invd;
            float dBi  = (dA1.i * Are - nr * Aim) * invd;
            float Cr   = C_re[pn];
            float Ci   = C_im[pn];
            if (wave == 0) { dBv_sh[2 * lane] = dBr; dBv_sh[2 * lane + 1] = dBi; }

            // G chain: role = even/odd element, seg = 11-step range
            const int role = wave & 1;
            const int seg  = wave >> 1;          // 0..5
            cx d2  = cmul(dA1, dA1);
            cx d4  = cmul(d2, d2);
            cx d8  = cmul(d4, d4);
            cx d11 = cmul(cmul(d8, d2), dA1);
            cx d22 = cmul(d11, d11);
            cx d44 = cmul(d22, d22);
            cx P = { 1.f, 0.f };
            if (seg & 1) P = cmul(P, d11);
            if (seg & 2) P = cmul(P, d22);
            if (seg & 4) P = cmul(P, d44);
            const int j0 = 11 * seg;
            const int jend = (j0 + 11 < 65) ? (j0 + 11) : 65;
            for (int j = j0; j < jend; ++j) {
                if (role == 0) G_lds[j][2 * lane]     = (f16)( 2.f * (Cr * P.r - Ci * P.i));
                else {
                    G_lds[j][2 * lane + 1] = (f16)(-2.f * (Cr * P.i + Ci * P.r));
                    if (j == 64) { w_sh[lane][0] = P.r; w_sh[lane][1] = P.i; }
                }
                P = cmul(P, dA1);
            }

            // scan waves: build E-fragments in registers for n_f = 16*wave+frow
            if (wave < 4) {
                const int nf  = 16 * wave + frow;
                const int pnf = ph * N_ST + nf;
                float AreF = -expf(log_A_re[pnf]);
                float AimF = A_im[pnf];
                float mgF  = expf(dt * AreF);
                float phF  = dt * AimF;
                cx dAf = { mgF * cosf(phF), mgF * sinf(phF) };
                float invF = 1.0f / (AreF * AreF + AimF * AimF);
                float nrF  = dAf.r - 1.0f;
                float dBrF = (nrF * AreF + dAf.i * AimF) * invF;
                float dBiF = (dAf.i * AreF - nrF * AimF) * invF;
                cx f2  = cmul(dAf, dAf);
                cx f4  = cmul(f2, f2);
                cx f8  = cmul(f4, f4);
                cx f16p = cmul(f8, f8);
                cx f32p = cmul(f16p, f16p);
                cx one = { 1.f, 0.f };
                // frag0: m = fk+q -> exponent 63-fk-q; walk q = 7..0 from dA^(8*(7-fq))
                cx Pa = f32p;
                Pa = cmul(Pa, (fq < 2) ? f16p : one);
                Pa = cmul(Pa, ((fq & 1) == 0) ? f8 : one);
#pragma unroll
                for (int q = 7; q >= 0; --q) {
                    aRe0[q] = (f16)(Pa.r * dBrF - Pa.i * dBiF);
                    aIm0[q] = (f16)(Pa.r * dBiF + Pa.i * dBrF);
                    Pa = cmul(Pa, dAf);
                }
                // frag1: m = 32+fk+q -> exponent 31-fk-q; start dA^(8*(3-fq))
                cx Pb = one;
                Pb = cmul(Pb, (fq < 2) ? f16p : one);
                Pb = cmul(Pb, ((fq & 1) == 0) ? f8 : one);
#pragma unroll
                for (int q = 7; q >= 0; --q) {
                    aRe1[q] = (f16)(Pb.r * dBrF - Pb.i * dBiF);
                    aIm1[q] = (f16)(Pb.r * dBiF + Pb.i * dBrF);
                    Pb = cmul(Pb, dAf);
                }
            }
        }
        barrier_lgkm();

        // ---- interval B: K[d] = G_ext[d] . dBv  (8 lanes per d) ----
        if (tid < 512) {
            const int t  = tid >> 3;
            const int l8 = tid & 7;
            f16x8 g0 = *(const f16x8*)&G_lds[t][l8 * 16];
            f16x8 g1 = *(const f16x8*)&G_lds[t][l8 * 16 + 8];
            f32x4 d0 = *(const f32x4*)&dBv_sh[l8 * 16];
            f32x4 d1 = *(const f32x4*)&dBv_sh[l8 * 16 + 4];
            f32x4 d2v = *(const f32x4*)&dBv_sh[l8 * 16 + 8];
            f32x4 d3 = *(const f32x4*)&dBv_sh[l8 * 16 + 12];
            float acc = 0.f;
#pragma unroll
            for (int k = 0; k < 4; ++k) {
                acc += (float)g0[k]     * d0[k];
                acc += (float)g0[k + 4] * d1[k];
                acc += (float)g1[k]     * d2v[k];
                acc += (float)g1[k + 4] * d3[k];
            }
            acc += __shfl_xor(acc, 1);
            acc += __shfl_xor(acc, 2);
            acc += __shfl_xor(acc, 4);
            if (l8 == 0) K_sh[t] = acc;
        }
        barrier_lgkm();

        // ---- interval C: Toeplitz expansion, D on diagonal ----
        for (int e = tid; e < 64 * 64; e += NTHR) {
            int i = e >> 6, jc = e & 63;
            A_lds[i][jc] = (jc < i) ? (f16)K_sh[i - jc]
                         : (jc == i ? (f16)(K_sh[0] + Dv) : (f16)0.f);
        }
        barrier_lgkm();

        // ---- fragment preload (out waves from LDS; scan w from w_sh) ----
        if (wave < 4) {
            const int m0 = 16 * wave;
#pragma unroll
            for (int p = 0; p < 4; ++p) {
                int n = m0 + fq * 4 + p;
                wr4[p] = w_sh[n][0]; wi4[p] = w_sh[n][1];
            }
        } else {
            const int mh = (wave - 4) & 1;
#pragma unroll
            for (int mt = 0; mt < 2; ++mt) {
                const int r0 = 32 * mh + 16 * mt + frow;
                aT0[mt] = *(const f16x8*)&A_lds[r0][fk];
                aT1[mt] = *(const f16x8*)&A_lds[r0][fk + 32];
#pragma unroll
                for (int k4 = 0; k4 < 4; ++k4)
                    aG[mt][k4] = *(const f16x8*)&G_lds[1 + r0][fk + 32 * k4];
            }
        }
        f16x4 yh[2];   // out: held y (layers 0-2), set at g>=1 before first use at g>=2
        barrier_lgkm();  // preload reads A_lds/G_lds done before next layer could touch; also orders w_sh

        // ---- main pipelined group loop: ONE barrier per group-iteration ----
        for (int g = 0; g <= N_GROUPS + 1; ++g) {
            if (wave < 4) {                      // ---- scan ----
                if (g < N_GROUPS) {
                    const int gb = g & 1;
#pragma unroll
                    for (int j = 0; j < GSZ; ++j) {
                        f16x8 sf;
                        sf[0] = (f16)s_r[0]; sf[1] = (f16)s_i[0];
                        sf[2] = (f16)s_r[1]; sf[3] = (f16)s_i[1];
                        sf[4] = (f16)s_r[2]; sf[5] = (f16)s_i[2];
                        sf[6] = (f16)s_r[3]; sf[7] = (f16)s_i[3];
                        if (frow < 8)
                            *(f16x8*)&S_buf[gb][j][frow][32 * wave + fk] = sf;
                        const int co = (g * GSZ + j) * 64;
                        f16x8 b0 = *(const f16x8*)&U_all[fr8][co + fk];
                        f16x8 b1 = *(const f16x8*)&U_all[fr8][co + fk + 32];
                        f32x4 aR = {0.f,0.f,0.f,0.f}, aI = {0.f,0.f,0.f,0.f};
                        aR = __builtin_amdgcn_mfma_f32_16x16x32_f16(aRe0, b0, aR, 0, 0, 0);
                        aR = __builtin_amdgcn_mfma_f32_16x16x32_f16(aRe1, b1, aR, 0, 0, 0);
                        aI = __builtin_amdgcn_mfma_f32_16x16x32_f16(aIm0, b0, aI, 0, 0, 0);
                        aI = __builtin_amdgcn_mfma_f32_16x16x32_f16(aIm1, b1, aI, 0, 0, 0);
#pragma unroll
                        for (int p = 0; p < 4; ++p) {
                            float nr2 = wr4[p] * s_r[p] - wi4[p] * s_i[p] + aR[p];
                            float ni2 = wi4[p] * s_r[p] + wr4[p] * s_i[p] + aI[p];
                            s_r[p] = nr2; s_i[p] = ni2;
                        }
                    }
                }
            } else {                             // ---- out: (chunk jc, m-half mh) ----
                const int ow = wave - 4, jc = ow >> 1, mh = ow & 1;
                if (layer < N_LAYERS - 1 && g >= 2 && frow < 8) {   // writeback group g-2
                    const int co2 = ((g - 2) * GSZ + jc) * 64;
                    *(f16x4*)&U_all[frow][co2 + 32 * mh + fq * 4]      = yh[0];
                    *(f16x4*)&U_all[frow][co2 + 32 * mh + 16 + fq * 4] = yh[1];
                }
                if (g >= 1 && g <= N_GROUPS) {           // compute group g-1
                    const int gp = g - 1, pb = gp & 1;
                    const int co = (gp * GSZ + jc) * 64;
                    f16x8 b0 = *(const f16x8*)&U_all[fr8][co + fk];
                    f16x8 b1 = *(const f16x8*)&U_all[fr8][co + fk + 32];
                    f16x8 sv0 = *(const f16x8*)&S_buf[pb][jc][fr8][fk];
                    f16x8 sv1 = *(const f16x8*)&S_buf[pb][jc][fr8][fk + 32];
                    f16x8 sv2 = *(const f16x8*)&S_buf[pb][jc][fr8][fk + 64];
                    f16x8 sv3 = *(const f16x8*)&S_buf[pb][jc][fr8][fk + 96];
#pragma unroll
                    for (int mt = 0; mt < 2; ++mt) {
                        f32x4 acc = {0.f,0.f,0.f,0.f};
                        acc = __builtin_amdgcn_mfma_f32_16x16x32_f16(aT0[mt], b0, acc, 0, 0, 0);
                        acc = __builtin_amdgcn_mfma_f32_16x16x32_f16(aT1[mt], b1, acc, 0, 0, 0);
                        acc = __builtin_amdgcn_mfma_f32_16x16x32_f16(aG[mt][0], sv0, acc, 0, 0, 0);
                        acc = __builtin_amdgcn_mfma_f32_16x16x32_f16(aG[mt][1], sv1, acc, 0, 0, 0);
                        acc = __builtin_amdgcn_mfma_f32_16x16x32_f16(aG[mt][2], sv2, acc, 0, 0, 0);
                        acc = __builtin_amdgcn_mfma_f32_16x16x32_f16(aG[mt][3], sv3, acc, 0, 0, 0);
                        const int t0 = 32 * mh + 16 * mt + fq * 4;
                        f16x4 o;
#pragma unroll
                        for (int k = 0; k < 4; ++k) o[k] = (f16)acc[k];
                        if (layer == N_LAYERS - 1) {
                            if (frow < 8)
                                *(f16x4*)&yb[(size_t)frow * L_SEQ + co + t0] = o;
                        } else {
                            yh[mt] = o;
                        }
                    }
                }
            }
            barrier_lgkm();
        }

        // ---- final states from scan registers ----
        if (wave < 4 && frow < 8) {
#pragma unroll
            for (int p = 0; p < 4; ++p) {
                int n = 16 * wave + 4 * fq + p;
                size_t base = (((size_t)layer * B_SZ + bh * BH + frow) * H_SZ + h) * N_ST + n;
                st_re[base] = s_r[p];
                st_im[base] = s_i[p];
            }
        }
        __syncthreads();   // tables / U_all safe to overwrite for next layer
    }
}

// ---------- [H][B][L] f16 -> [L][B][H] f32 transpose ----------
__global__ __launch_bounds__(256, 4)
void hbl_to_lbh_kernel(const f16* __restrict__ in, float* __restrict__ out)
{
    __shared__ float t_sh[64][65];
    const int tid = threadIdx.x, bid = blockIdx.x;
    const int bb = bid & 15, lt = (bid >> 4) & 31, ht = bid >> 9;
    const int l0 = lt * 64, h0 = ht * 64;
#pragma unroll
    for (int i = 0; i < 4; ++i) {
        int idx = tid + i * 256;
        int hh = idx >> 4, l4 = (idx & 15) * 4;
        f16x4 v = *(const f16x4*)&in[((size_t)(h0 + hh) * B_SZ + bb) * L_SEQ + l0 + l4];
#pragma unroll
        for (int k = 0; k < 4; ++k) t_sh[hh][l4 + k] = (float)v[k];
    }
    __syncthreads();
#pragma unroll
    for (int i = 0; i < 4; ++i) {
        int idx = tid + i * 256;
        int ll = idx >> 4, h4 = (idx & 15) * 4;
        float4 o = make_float4(t_sh[h4][ll], t_sh[h4 + 1][ll],
                               t_sh[h4 + 2][ll], t_sh[h4 + 3][ll]);
        *(float4*)&out[((size_t)(l0 + ll) * B_SZ + bb) * H_SZ + h0 + h4] = o;
    }
}

extern "C" void kernel_launch(void* const* d_in, const int* in_sizes, int n_in,
                              void* d_out, int out_size, void* d_ws, size_t ws_size,
                              hipStream_t stream)
{
    const float* x        = (const float*)d_in[0];
    const float* enc_W    = (const float*)d_in[1];
    const float* enc_b    = (const float*)d_in[2];
    const float* log_dt   = (const float*)d_in[3];
    const float* log_A_re = (const float*)d_in[4];
    const float* A_im     = (const float*)d_in[5];
    const float* C_re     = (const float*)d_in[6];
    const float* C_im     = (const float*)d_in[7];
    const float* Dskip    = (const float*)d_in[8];

    float* out_lbh = (float*)d_out;                                  // [L,B,H]
    float* st_re   = out_lbh + (size_t)L_SEQ * B_SZ * H_SZ;
    float* st_im   = st_re + (size_t)N_LAYERS * B_SZ * H_SZ * N_ST;
    f16*   B0      = (f16*)d_ws;     // [H][B][L] f16 activations (32 MB)

    encoder_mfma_kernel<<<4096, 256, 0, stream>>>(x, enc_W, enc_b, B0);

    s4d_fused_kernel<<<1024, NTHR, 0, stream>>>(B0, log_dt, log_A_re, A_im,
                                                C_re, C_im, Dskip, st_re, st_im);

    hbl_to_lbh_kernel<<<4096, 256, 0, stream>>>(B0, out_lbh);        // final y -> [L,B,H]
}

// Round 10
// 374.506 us; speedup vs baseline: 2.3377x; 2.3377x over previous
//
#include <hip/hip_runtime.h>
#include <math.h>

#define L_SEQ 2048
#define B_SZ 16
#define DIN 64
#define H_SZ 512
#define N_ST 64
#define N_LAYERS 4
#define Q_CHUNK 64
#define N_CHUNKS (L_SEQ / Q_CHUNK)   // 32
#define GSZ 4                         // chunks per pipeline group
#define N_GROUPS (N_CHUNKS / GSZ)     // 8
#define UPAD 2056                     // U_all row stride in f16 (16B-aligned)
#define NTHR 512                      // 8 waves: 4 scan + 4 out
#define BH 8                          // batch rows per block (B-split)

typedef _Float16 f16;
typedef _Float16 f16x8 __attribute__((ext_vector_type(8)));
typedef _Float16 f16x4 __attribute__((ext_vector_type(4)));
typedef float    f32x4 __attribute__((ext_vector_type(4)));

struct cx { float r, i; };
__device__ __forceinline__ cx cmul(cx a, cx b) {
    return { a.r * b.r - a.i * b.i, a.r * b.i + a.i * b.r };
}

// LDS-only barrier (global loads/stores may stay in flight across it)
__device__ __forceinline__ void barrier_lgkm() {
    asm volatile("s_waitcnt lgkmcnt(0)\n\ts_barrier" ::: "memory");
}

// ---------- encoder (MFMA): out[h][b][l] = f16( sum_k x[l][b][k] W[k][h] + bias[h] ) ----------
__global__ __launch_bounds__(256, 4)
void encoder_mfma_kernel(const float* __restrict__ x, const float* __restrict__ W,
                         const float* __restrict__ bias, f16* __restrict__ out)
{
    __shared__ f16   x_sh[64][72];    // [l][k]
    __shared__ f16   w_t[64][72];     // [h][k]
    __shared__ float out_sh[64][68];
    __shared__ float b_sh[64];
    const int tid = threadIdx.x;
    const int bid = blockIdx.x;
    const int bb  = bid & 15;
    const int lt  = (bid >> 4) & 31;
    const int ht  = bid >> 9;
    const int l0 = lt * 64, h0 = ht * 64;

#pragma unroll
    for (int i = 0; i < 4; ++i) {
        int e  = tid + i * 256;            // 0..1023
        int r  = e >> 4;                   // 0..63 (l for x, k for W)
        int c4 = (e & 15) * 4;             // 0..60
        float4 xv = *(const float4*)&x[((size_t)(l0 + r) * B_SZ + bb) * DIN + c4];
        f16x4 xo; xo[0] = (f16)xv.x; xo[1] = (f16)xv.y; xo[2] = (f16)xv.z; xo[3] = (f16)xv.w;
        *(f16x4*)&x_sh[r][c4] = xo;        // [l][k]
        float4 wv = *(const float4*)&W[(size_t)r * H_SZ + h0 + c4];
        w_t[c4 + 0][r] = (f16)wv.x;        // [h][k] (transposed scatter)
        w_t[c4 + 1][r] = (f16)wv.y;
        w_t[c4 + 2][r] = (f16)wv.z;
        w_t[c4 + 3][r] = (f16)wv.w;
    }
    if (tid < 64) b_sh[tid] = bias[h0 + tid];
    __syncthreads();

    const int wave = tid >> 6;
    const int lane = tid & 63;
    const int frow = lane & 15;
    const int fk   = (lane >> 4) * 8;
    const int m0   = wave * 16;            // h strip per wave

    f16x8 a0 = *(const f16x8*)&w_t[m0 + frow][fk];
    f16x8 a1 = *(const f16x8*)&w_t[m0 + frow][fk + 32];
    float bv[4];
#pragma unroll
    for (int j = 0; j < 4; ++j) bv[j] = b_sh[m0 + (lane >> 4) * 4 + j];

#pragma unroll
    for (int nt = 0; nt < 4; ++nt) {       // l tiles
        f16x8 b0 = *(const f16x8*)&x_sh[nt * 16 + frow][fk];
        f16x8 b1 = *(const f16x8*)&x_sh[nt * 16 + frow][fk + 32];
        f32x4 acc = {0.f, 0.f, 0.f, 0.f};
        acc = __builtin_amdgcn_mfma_f32_16x16x32_f16(a0, b0, acc, 0, 0, 0);
        acc = __builtin_amdgcn_mfma_f32_16x16x32_f16(a1, b1, acc, 0, 0, 0);
#pragma unroll
        for (int j = 0; j < 4; ++j)
            out_sh[m0 + (lane >> 4) * 4 + j][nt * 16 + frow] = acc[j] + bv[j];
    }
    __syncthreads();

#pragma unroll
    for (int i = 0; i < 4; ++i) {
        int row = (tid >> 4) + i * 16;     // h row
        int c4  = (tid & 15) * 4;          // l col
        f32x4 v = *(const f32x4*)&out_sh[row][c4];
        f16x4 o;
#pragma unroll
        for (int k = 0; k < 4; ++k) o[k] = (f16)v[k];
        *(f16x4*)&out[((size_t)(h0 + row) * B_SZ + bb) * L_SEQ + l0 + c4] = o;
    }
}

// ---------- fused 4-layer S4D, B-split: one block per (h, 8-batch half) ----------
// 512 threads = 8 waves; LDS 78.5 KB; __launch_bounds__(512, 4) -> VGPR cap 128
// => 2 blocks/CU resident (round-9's spill came from the 85-VGPR cap of 12
// waves @ 6/SIMD; 8 waves @ 4/SIMD caps at 128, above this kernel's ~100 need).
//   waves 0-3 ("scan"): wave w owns n in [16w,16w+16): publish S_pre -> S_buf;
//                       Z = E.U (4 MFMA, E frags REGISTER-built, HW-verified
//                       round 9); register scan, 4 complex pairs/lane.
//   waves 4-7 ("out"):  wave = (m-half mh=ow&1, chunk-pair ow>>1):
//                       per group-iter 2 chunks x 12 MFMA, same 12-frag set as
//                       round 7 (48 VGPR); writeback lag 2; global store layer 3.
// MFMA b-row = frow&7 (rows 8-15 broadcast duplicates); stores predicated frow<8.
__global__ __launch_bounds__(NTHR, 4)
void s4d_fused_kernel(f16* __restrict__ u_io,          // [H][B][L] f16: encoder out; final y in place
                      const float* __restrict__ log_dt, const float* __restrict__ log_A_re,
                      const float* __restrict__ A_im, const float* __restrict__ C_re,
                      const float* __restrict__ C_im, const float* __restrict__ Dskip,
                      float* __restrict__ st_re, float* __restrict__ st_im)
{
    __shared__ f16   A_lds[64][72];          //  9216 B: Toeplitz(K)+D.I
    __shared__ f16   G_lds[65][136];         // 17680 B: G_ext[j][n2], j=0..64
    __shared__ f16   U_all[BH][UPAD];        // 32896 B: per-(h,bh) sequence, in place
    __shared__ f16   S_buf[2][GSZ][BH][136]; // 17408 B: S_pre per chunk of group
    __shared__ float dBv_sh[128];            //   512 B
    __shared__ float K_sh[64];               //   256 B
    __shared__ float w_sh[64][2];            //   512 B
    // total 78480 B -> 2 blocks/CU

    const int tid  = threadIdx.x;
    const int wave = tid >> 6;
    const int lane = tid & 63;
    const int h    = blockIdx.x >> 1;
    const int bh   = blockIdx.x & 1;         // batch half
    const int frow = lane & 15;
    const int fq   = lane >> 4;
    const int fk   = fq * 8;
    const int fr8  = frow & 7;               // MFMA b-row within 8 (rows 8-15 duplicate)

    // ---- stage this block's 8 batch rows into LDS ----
    {
        const f16* ub = u_io + ((size_t)h * B_SZ + bh * BH) * L_SEQ;
        for (int u0 = tid; u0 < BH * 256; u0 += NTHR) {
            int b = u0 >> 8, cidx = (u0 & 255) * 8;
            *(f16x8*)&U_all[b][cidx] = *(const f16x8*)&ub[(size_t)b * L_SEQ + cidx];
        }
    }
    f16* yb = u_io + ((size_t)h * B_SZ + bh * BH) * L_SEQ;   // final-layer f16 output

    for (int layer = 0; layer < N_LAYERS; ++layer) {
        const int ph = layer * H_SZ + h;
        const int pn = ph * N_ST + lane;
        const float Dv = Dskip[ph];          // folded into Toeplitz diagonal

        // fragments (persist through the layer)
        f16x8 aRe0, aRe1, aIm0, aIm1;        // scan (register-built E)
        f16x8 aT0[2], aT1[2], aG[2][4];      // out
        float wr4[4], wi4[4];
        float s_r[4] = {0.f,0.f,0.f,0.f}, s_i[4] = {0.f,0.f,0.f,0.f};

        // ---- interval A: G chains (4-way, 17 steps) + dBv + w + per-lane E-frag build ----
        {
            float dt   = expf(log_dt[ph]);
            float Are  = -expf(log_A_re[pn]);
            float Aim  = A_im[pn];
            float mg   = expf(dt * Are);
            float phs  = dt * Aim;
            cx dA1 = { mg * cosf(phs), mg * sinf(phs) };
            float invd = 1.0f / (Are * Are + Aim * Aim);
            float nr   = dA1.r - 1.0f;
            float dBr  = (nr * Are + dA1.i * Aim) * invd;
            float dBi  = (dA1.i * Are - nr * Aim) * invd;
            float Cr   = C_re[pn];
            float Ci   = C_im[pn];
            if (wave == 0) { dBv_sh[2 * lane] = dBr; dBv_sh[2 * lane + 1] = dBi; }

            // G chain: role = even/odd element, seg = 17-step range (0..3)
            const int role = wave & 1;
            const int seg  = wave >> 1;
            cx d2  = cmul(dA1, dA1);
            cx d4  = cmul(d2, d2);
            cx d8  = cmul(d4, d4);
            cx d16 = cmul(d8, d8);
            cx d17 = cmul(d16, dA1);
            cx d34 = cmul(d17, d17);
            cx P = { 1.f, 0.f };
            if (seg & 1) P = cmul(P, d17);
            if (seg & 2) P = cmul(P, d34);
            const int j0 = 17 * seg;
            const int jend = (j0 + 17 < 65) ? (j0 + 17) : 65;
            for (int j = j0; j < jend; ++j) {
                if (role == 0) G_lds[j][2 * lane]     = (f16)( 2.f * (Cr * P.r - Ci * P.i));
                else {
                    G_lds[j][2 * lane + 1] = (f16)(-2.f * (Cr * P.i + Ci * P.r));
                    if (j == 64) { w_sh[lane][0] = P.r; w_sh[lane][1] = P.i; }
                }
                P = cmul(P, dA1);
            }

            // scan waves: build E-fragments in registers for n_f = 16*wave+frow
            // (index algebra HW-verified in round 9: absmax passed)
            if (wave < 4) {
                const int nf  = 16 * wave + frow;
                const int pnf = ph * N_ST + nf;
                float AreF = -expf(log_A_re[pnf]);
                float AimF = A_im[pnf];
                float mgF  = expf(dt * AreF);
                float phF  = dt * AimF;
                cx dAf = { mgF * cosf(phF), mgF * sinf(phF) };
                float invF = 1.0f / (AreF * AreF + AimF * AimF);
                float nrF  = dAf.r - 1.0f;
                float dBrF = (nrF * AreF + dAf.i * AimF) * invF;
                float dBiF = (dAf.i * AreF - nrF * AimF) * invF;
                cx f2  = cmul(dAf, dAf);
                cx f4  = cmul(f2, f2);
                cx f8  = cmul(f4, f4);
                cx f16p = cmul(f8, f8);
                cx f32p = cmul(f16p, f16p);
                cx one = { 1.f, 0.f };
                // frag0: col m = fk+q -> exponent 63-fk-q; walk q=7..0 from dA^(8*(7-fq))
                cx Pa = f32p;
                Pa = cmul(Pa, (fq < 2) ? f16p : one);
                Pa = cmul(Pa, ((fq & 1) == 0) ? f8 : one);
#pragma unroll
                for (int q = 7; q >= 0; --q) {
                    aRe0[q] = (f16)(Pa.r * dBrF - Pa.i * dBiF);
                    aIm0[q] = (f16)(Pa.r * dBiF + Pa.i * dBrF);
                    Pa = cmul(Pa, dAf);
                }
                // frag1: col m = 32+fk+q -> exponent 31-fk-q; start dA^(8*(3-fq))
                cx Pb = one;
                Pb = cmul(Pb, (fq < 2) ? f16p : one);
                Pb = cmul(Pb, ((fq & 1) == 0) ? f8 : one);
#pragma unroll
                for (int q = 7; q >= 0; --q) {
                    aRe1[q] = (f16)(Pb.r * dBrF - Pb.i * dBiF);
                    aIm1[q] = (f16)(Pb.r * dBiF + Pb.i * dBrF);
                    Pb = cmul(Pb, dAf);
                }
            }
        }
        barrier_lgkm();

        // ---- interval B: K[d] = G_ext[d] . dBv  (8 lanes per d, 512 thr) ----
        {
            const int t  = tid >> 3;
            const int l8 = tid & 7;
            f16x8 g0 = *(const f16x8*)&G_lds[t][l8 * 16];
            f16x8 g1 = *(const f16x8*)&G_lds[t][l8 * 16 + 8];
            f32x4 d0 = *(const f32x4*)&dBv_sh[l8 * 16];
            f32x4 d1 = *(const f32x4*)&dBv_sh[l8 * 16 + 4];
            f32x4 d2v = *(const f32x4*)&dBv_sh[l8 * 16 + 8];
            f32x4 d3 = *(const f32x4*)&dBv_sh[l8 * 16 + 12];
            float acc = 0.f;
#pragma unroll
            for (int k = 0; k < 4; ++k) {
                acc += (float)g0[k]     * d0[k];
                acc += (float)g0[k + 4] * d1[k];
                acc += (float)g1[k]     * d2v[k];
                acc += (float)g1[k + 4] * d3[k];
            }
            acc += __shfl_xor(acc, 1);
            acc += __shfl_xor(acc, 2);
            acc += __shfl_xor(acc, 4);
            if (l8 == 0) K_sh[t] = acc;
        }
        barrier_lgkm();

        // ---- interval C: Toeplitz expansion, D on diagonal ----
        for (int e = tid; e < 64 * 64; e += NTHR) {
            int i = e >> 6, jc = e & 63;
            A_lds[i][jc] = (jc < i) ? (f16)K_sh[i - jc]
                         : (jc == i ? (f16)(K_sh[0] + Dv) : (f16)0.f);
        }
        barrier_lgkm();

        // ---- fragment preload (out waves from LDS; scan w from w_sh) ----
        if (wave < 4) {
            const int m0 = 16 * wave;
#pragma unroll
            for (int p = 0; p < 4; ++p) {
                int n = m0 + fq * 4 + p;
                wr4[p] = w_sh[n][0]; wi4[p] = w_sh[n][1];
            }
        } else {
            const int mh = (wave - 4) & 1;
#pragma unroll
            for (int mt = 0; mt < 2; ++mt) {
                const int r0 = 32 * mh + 16 * mt + frow;
                aT0[mt] = *(const f16x8*)&A_lds[r0][fk];
                aT1[mt] = *(const f16x8*)&A_lds[r0][fk + 32];
#pragma unroll
                for (int k4 = 0; k4 < 4; ++k4)
                    aG[mt][k4] = *(const f16x8*)&G_lds[1 + r0][fk + 32 * k4];
            }
        }
        f16x4 yh[2][2];  // out: held y [jj][mt] (layers 0-2), static-indexed
        barrier_lgkm();  // preload reads done before main loop overwrites anything

        // ---- main pipelined group loop: ONE barrier per group-iteration ----
        for (int g = 0; g <= N_GROUPS + 1; ++g) {
            if (wave < 4) {                      // ---- scan ----
                if (g < N_GROUPS) {
                    const int gb = g & 1;
#pragma unroll
                    for (int j = 0; j < GSZ; ++j) {
                        f16x8 sf;
                        sf[0] = (f16)s_r[0]; sf[1] = (f16)s_i[0];
                        sf[2] = (f16)s_r[1]; sf[3] = (f16)s_i[1];
                        sf[4] = (f16)s_r[2]; sf[5] = (f16)s_i[2];
                        sf[6] = (f16)s_r[3]; sf[7] = (f16)s_i[3];
                        if (frow < 8)
                            *(f16x8*)&S_buf[gb][j][frow][32 * wave + fk] = sf;
                        const int co = (g * GSZ + j) * 64;
                        f16x8 b0 = *(const f16x8*)&U_all[fr8][co + fk];
                        f16x8 b1 = *(const f16x8*)&U_all[fr8][co + fk + 32];
                        f32x4 aR = {0.f,0.f,0.f,0.f}, aI = {0.f,0.f,0.f,0.f};
                        aR = __builtin_amdgcn_mfma_f32_16x16x32_f16(aRe0, b0, aR, 0, 0, 0);
                        aR = __builtin_amdgcn_mfma_f32_16x16x32_f16(aRe1, b1, aR, 0, 0, 0);
                        aI = __builtin_amdgcn_mfma_f32_16x16x32_f16(aIm0, b0, aI, 0, 0, 0);
                        aI = __builtin_amdgcn_mfma_f32_16x16x32_f16(aIm1, b1, aI, 0, 0, 0);
#pragma unroll
                        for (int p = 0; p < 4; ++p) {
                            float nr2 = wr4[p] * s_r[p] - wi4[p] * s_i[p] + aR[p];
                            float ni2 = wi4[p] * s_r[p] + wr4[p] * s_i[p] + aI[p];
                            s_r[p] = nr2; s_i[p] = ni2;
                        }
                    }
                }
            } else {                             // ---- out: (m-half mh, chunk-pair jcp) ----
                const int ow = wave - 4, mh = ow & 1, jcp = ow >> 1;
                if (layer < N_LAYERS - 1 && g >= 2 && frow < 8) {   // writeback group g-2
#pragma unroll
                    for (int jj = 0; jj < 2; ++jj) {
                        const int co2 = ((g - 2) * GSZ + jcp * 2 + jj) * 64;
                        *(f16x4*)&U_all[frow][co2 + 32 * mh + fq * 4]      = yh[jj][0];
                        *(f16x4*)&U_all[frow][co2 + 32 * mh + 16 + fq * 4] = yh[jj][1];
                    }
                }
                if (g >= 1 && g <= N_GROUPS) {           // compute group g-1
                    const int gp = g - 1, pb = gp & 1;
#pragma unroll
                    for (int jj = 0; jj < 2; ++jj) {
                        const int jc = jcp * 2 + jj;
                        const int co = (gp * GSZ + jc) * 64;
                        f16x8 b0 = *(const f16x8*)&U_all[fr8][co + fk];
                        f16x8 b1 = *(const f16x8*)&U_all[fr8][co + fk + 32];
                        f16x8 sv0 = *(const f16x8*)&S_buf[pb][jc][fr8][fk];
                        f16x8 sv1 = *(const f16x8*)&S_buf[pb][jc][fr8][fk + 32];
                        f16x8 sv2 = *(const f16x8*)&S_buf[pb][jc][fr8][fk + 64];
                        f16x8 sv3 = *(const f16x8*)&S_buf[pb][jc][fr8][fk + 96];
#pragma unroll
                        for (int mt = 0; mt < 2; ++mt) {
                            f32x4 acc = {0.f,0.f,0.f,0.f};
                            acc = __builtin_amdgcn_mfma_f32_16x16x32_f16(aT0[mt], b0, acc, 0, 0, 0);
                            acc = __builtin_amdgcn_mfma_f32_16x16x32_f16(aT1[mt], b1, acc, 0, 0, 0);
                            acc = __builtin_amdgcn_mfma_f32_16x16x32_f16(aG[mt][0], sv0, acc, 0, 0, 0);
                            acc = __builtin_amdgcn_mfma_f32_16x16x32_f16(aG[mt][1], sv1, acc, 0, 0, 0);
                            acc = __builtin_amdgcn_mfma_f32_16x16x32_f16(aG[mt][2], sv2, acc, 0, 0, 0);
                            acc = __builtin_amdgcn_mfma_f32_16x16x32_f16(aG[mt][3], sv3, acc, 0, 0, 0);
                            const int t0 = 32 * mh + 16 * mt + fq * 4;
                            f16x4 o;
#pragma unroll
                            for (int k = 0; k < 4; ++k) o[k] = (f16)acc[k];
                            if (layer == N_LAYERS - 1) {
                                if (frow < 8)
                                    *(f16x4*)&yb[(size_t)frow * L_SEQ + co + t0] = o;
                            } else {
                                yh[jj][mt] = o;
                            }
                        }
                    }
                }
            }
            barrier_lgkm();
        }

        // ---- final states from scan registers ----
        if (wave < 4 && frow < 8) {
#pragma unroll
            for (int p = 0; p < 4; ++p) {
                int n = 16 * wave + 4 * fq + p;
                size_t base = (((size_t)layer * B_SZ + bh * BH + frow) * H_SZ + h) * N_ST + n;
                st_re[base] = s_r[p];
                st_im[base] = s_i[p];
            }
        }
        __syncthreads();   // tables / U_all safe to overwrite for next layer
    }
}

// ---------- [H][B][L] f16 -> [L][B][H] f32 transpose ----------
__global__ __launch_bounds__(256, 4)
void hbl_to_lbh_kernel(const f16* __restrict__ in, float* __restrict__ out)
{
    __shared__ float t_sh[64][65];
    const int tid = threadIdx.x, bid = blockIdx.x;
    const int bb = bid & 15, lt = (bid >> 4) & 31, ht = bid >> 9;
    const int l0 = lt * 64, h0 = ht * 64;
#pragma unroll
    for (int i = 0; i < 4; ++i) {
        int idx = tid + i * 256;
        int hh = idx >> 4, l4 = (idx & 15) * 4;
        f16x4 v = *(const f16x4*)&in[((size_t)(h0 + hh) * B_SZ + bb) * L_SEQ + l0 + l4];
#pragma unroll
        for (int k = 0; k < 4; ++k) t_sh[hh][l4 + k] = (float)v[k];
    }
    __syncthreads();
#pragma unroll
    for (int i = 0; i < 4; ++i) {
        int idx = tid + i * 256;
        int ll = idx >> 4, h4 = (idx & 15) * 4;
        float4 o = make_float4(t_sh[h4][ll], t_sh[h4 + 1][ll],
                               t_sh[h4 + 2][ll], t_sh[h4 + 3][ll]);
        *(float4*)&out[((size_t)(l0 + ll) * B_SZ + bb) * H_SZ + h0 + h4] = o;
    }
}

extern "C" void kernel_launch(void* const* d_in, const int* in_sizes, int n_in,
                              void* d_out, int out_size, void* d_ws, size_t ws_size,
                              hipStream_t stream)
{
    const float* x        = (const float*)d_in[0];
    const float* enc_W    = (const float*)d_in[1];
    const float* enc_b    = (const float*)d_in[2];
    const float* log_dt   = (const float*)d_in[3];
    const float* log_A_re = (const float*)d_in[4];
    const float* A_im     = (const float*)d_in[5];
    const float* C_re     = (const float*)d_in[6];
    const float* C_im     = (const float*)d_in[7];
    const float* Dskip    = (const float*)d_in[8];

    float* out_lbh = (float*)d_out;                                  // [L,B,H]
    float* st_re   = out_lbh + (size_t)L_SEQ * B_SZ * H_SZ;
    float* st_im   = st_re + (size_t)N_LAYERS * B_SZ * H_SZ * N_ST;
    f16*   B0      = (f16*)d_ws;     // [H][B][L] f16 activations (32 MB)

    encoder_mfma_kernel<<<4096, 256, 0, stream>>>(x, enc_W, enc_b, B0);

    s4d_fused_kernel<<<1024, NTHR, 0, stream>>>(B0, log_dt, log_A_re, A_im,
                                                C_re, C_im, Dskip, st_re, st_im);

    hbl_to_lbh_kernel<<<4096, 256, 0, stream>>>(B0, out_lbh);        // final y -> [L,B,H]
}

// Round 11
// 318.883 us; speedup vs baseline: 2.7455x; 1.1744x over previous
//
#include <hip/hip_runtime.h>
#include <math.h>

#define L_SEQ 2048
#define B_SZ 16
#define DIN 64
#define H_SZ 512
#define N_ST 64
#define N_LAYERS 4
#define Q_CHUNK 64
#define N_CHUNKS (L_SEQ / Q_CHUNK)   // 32
#define GSZ 4                         // chunks per pipeline group
#define N_GROUPS (N_CHUNKS / GSZ)     // 8
#define UPAD 2056                     // U_all row stride in f16 (16B-aligned)
#define NTHR 512                      // 8 waves: 4 scan + 4 out
#define BH 8                          // batch rows per block (B-split)

typedef _Float16 f16;
typedef _Float16 f16x8 __attribute__((ext_vector_type(8)));
typedef _Float16 f16x4 __attribute__((ext_vector_type(4)));
typedef float    f32x4 __attribute__((ext_vector_type(4)));

struct cx { float r, i; };
__device__ __forceinline__ cx cmul(cx a, cx b) {
    return { a.r * b.r - a.i * b.i, a.r * b.i + a.i * b.r };
}

// LDS-only barrier (global loads/stores may stay in flight across it)
__device__ __forceinline__ void barrier_lgkm() {
    asm volatile("s_waitcnt lgkmcnt(0)\n\ts_barrier" ::: "memory");
}

// ---------- encoder (MFMA): out[h][b][l] = f16( sum_k x[l][b][k] W[k][h] + bias[h] ) ----------
__global__ __launch_bounds__(256, 4)
void encoder_mfma_kernel(const float* __restrict__ x, const float* __restrict__ W,
                         const float* __restrict__ bias, f16* __restrict__ out)
{
    __shared__ f16   x_sh[64][72];    // [l][k]
    __shared__ f16   w_t[64][72];     // [h][k]
    __shared__ float out_sh[64][68];
    __shared__ float b_sh[64];
    const int tid = threadIdx.x;
    const int bid = blockIdx.x;
    const int bb  = bid & 15;
    const int lt  = (bid >> 4) & 31;
    const int ht  = bid >> 9;
    const int l0 = lt * 64, h0 = ht * 64;

#pragma unroll
    for (int i = 0; i < 4; ++i) {
        int e  = tid + i * 256;            // 0..1023
        int r  = e >> 4;                   // 0..63 (l for x, k for W)
        int c4 = (e & 15) * 4;             // 0..60
        float4 xv = *(const float4*)&x[((size_t)(l0 + r) * B_SZ + bb) * DIN + c4];
        f16x4 xo; xo[0] = (f16)xv.x; xo[1] = (f16)xv.y; xo[2] = (f16)xv.z; xo[3] = (f16)xv.w;
        *(f16x4*)&x_sh[r][c4] = xo;        // [l][k]
        float4 wv = *(const float4*)&W[(size_t)r * H_SZ + h0 + c4];
        w_t[c4 + 0][r] = (f16)wv.x;        // [h][k] (transposed scatter)
        w_t[c4 + 1][r] = (f16)wv.y;
        w_t[c4 + 2][r] = (f16)wv.z;
        w_t[c4 + 3][r] = (f16)wv.w;
    }
    if (tid < 64) b_sh[tid] = bias[h0 + tid];
    __syncthreads();

    const int wave = tid >> 6;
    const int lane = tid & 63;
    const int frow = lane & 15;
    const int fk   = (lane >> 4) * 8;
    const int m0   = wave * 16;            // h strip per wave

    f16x8 a0 = *(const f16x8*)&w_t[m0 + frow][fk];
    f16x8 a1 = *(const f16x8*)&w_t[m0 + frow][fk + 32];
    float bv[4];
#pragma unroll
    for (int j = 0; j < 4; ++j) bv[j] = b_sh[m0 + (lane >> 4) * 4 + j];

#pragma unroll
    for (int nt = 0; nt < 4; ++nt) {       // l tiles
        f16x8 b0 = *(const f16x8*)&x_sh[nt * 16 + frow][fk];
        f16x8 b1 = *(const f16x8*)&x_sh[nt * 16 + frow][fk + 32];
        f32x4 acc = {0.f, 0.f, 0.f, 0.f};
        acc = __builtin_amdgcn_mfma_f32_16x16x32_f16(a0, b0, acc, 0, 0, 0);
        acc = __builtin_amdgcn_mfma_f32_16x16x32_f16(a1, b1, acc, 0, 0, 0);
#pragma unroll
        for (int j = 0; j < 4; ++j)
            out_sh[m0 + (lane >> 4) * 4 + j][nt * 16 + frow] = acc[j] + bv[j];
    }
    __syncthreads();

#pragma unroll
    for (int i = 0; i < 4; ++i) {
        int row = (tid >> 4) + i * 16;     // h row
        int c4  = (tid & 15) * 4;          // l col
        f32x4 v = *(const f32x4*)&out_sh[row][c4];
        f16x4 o;
#pragma unroll
        for (int k = 0; k < 4; ++k) o[k] = (f16)v[k];
        *(f16x4*)&out[((size_t)(h0 + row) * B_SZ + bb) * L_SEQ + l0 + c4] = o;
    }
}

// ---------- fused 4-layer S4D, B-split: one block per (h, 8-batch half) ----------
// IDENTICAL to round 10 except __launch_bounds__(512, 2):
// round 10's (512,4) drove the allocator to a 64-VGPR budget (8 waves/SIMD
// target) -> massive scratch spill (FETCH 110 MB / WRITE 214 MB). (512,2)
// raises the register cap (>=128 under either waves-per-EU or blocks-per-CU
// semantics) while LDS (78.5 KB) still admits 2 blocks/CU.
//   waves 0-3 ("scan"): wave w owns n in [16w,16w+16): publish S_pre -> S_buf;
//                       Z = E.U (4 MFMA, E frags REGISTER-built, HW-verified);
//                       register scan, 4 complex pairs/lane.
//   waves 4-7 ("out"):  wave = (m-half mh=ow&1, chunk-pair ow>>1):
//                       per group-iter 2 chunks x 12 MFMA (round-7 frag set);
//                       writeback lag 2; global store layer 3.
// MFMA b-row = frow&7 (rows 8-15 broadcast duplicates); stores predicated frow<8.
__global__ __launch_bounds__(NTHR, 2)
void s4d_fused_kernel(f16* __restrict__ u_io,          // [H][B][L] f16: encoder out; final y in place
                      const float* __restrict__ log_dt, const float* __restrict__ log_A_re,
                      const float* __restrict__ A_im, const float* __restrict__ C_re,
                      const float* __restrict__ C_im, const float* __restrict__ Dskip,
                      float* __restrict__ st_re, float* __restrict__ st_im)
{
    __shared__ f16   A_lds[64][72];          //  9216 B: Toeplitz(K)+D.I
    __shared__ f16   G_lds[65][136];         // 17680 B: G_ext[j][n2], j=0..64
    __shared__ f16   U_all[BH][UPAD];        // 32896 B: per-(h,bh) sequence, in place
    __shared__ f16   S_buf[2][GSZ][BH][136]; // 17408 B: S_pre per chunk of group
    __shared__ float dBv_sh[128];            //   512 B
    __shared__ float K_sh[64];               //   256 B
    __shared__ float w_sh[64][2];            //   512 B
    // total 78480 B -> 2 blocks/CU

    const int tid  = threadIdx.x;
    const int wave = tid >> 6;
    const int lane = tid & 63;
    const int h    = blockIdx.x >> 1;
    const int bh   = blockIdx.x & 1;         // batch half
    const int frow = lane & 15;
    const int fq   = lane >> 4;
    const int fk   = fq * 8;
    const int fr8  = frow & 7;               // MFMA b-row within 8 (rows 8-15 duplicate)

    // ---- stage this block's 8 batch rows into LDS ----
    {
        const f16* ub = u_io + ((size_t)h * B_SZ + bh * BH) * L_SEQ;
        for (int u0 = tid; u0 < BH * 256; u0 += NTHR) {
            int b = u0 >> 8, cidx = (u0 & 255) * 8;
            *(f16x8*)&U_all[b][cidx] = *(const f16x8*)&ub[(size_t)b * L_SEQ + cidx];
        }
    }
    f16* yb = u_io + ((size_t)h * B_SZ + bh * BH) * L_SEQ;   // final-layer f16 output

    for (int layer = 0; layer < N_LAYERS; ++layer) {
        const int ph = layer * H_SZ + h;
        const int pn = ph * N_ST + lane;
        const float Dv = Dskip[ph];          // folded into Toeplitz diagonal

        // fragments (persist through the layer)
        f16x8 aRe0, aRe1, aIm0, aIm1;        // scan (register-built E)
        f16x8 aT0[2], aT1[2], aG[2][4];      // out
        float wr4[4], wi4[4];
        float s_r[4] = {0.f,0.f,0.f,0.f}, s_i[4] = {0.f,0.f,0.f,0.f};

        // ---- interval A: G chains (4-way, 17 steps) + dBv + w + per-lane E-frag build ----
        {
            float dt   = expf(log_dt[ph]);
            float Are  = -expf(log_A_re[pn]);
            float Aim  = A_im[pn];
            float mg   = expf(dt * Are);
            float phs  = dt * Aim;
            cx dA1 = { mg * cosf(phs), mg * sinf(phs) };
            float invd = 1.0f / (Are * Are + Aim * Aim);
            float nr   = dA1.r - 1.0f;
            float dBr  = (nr * Are + dA1.i * Aim) * invd;
            float dBi  = (dA1.i * Are - nr * Aim) * invd;
            float Cr   = C_re[pn];
            float Ci   = C_im[pn];
            if (wave == 0) { dBv_sh[2 * lane] = dBr; dBv_sh[2 * lane + 1] = dBi; }

            // G chain: role = even/odd element, seg = 17-step range (0..3)
            const int role = wave & 1;
            const int seg  = wave >> 1;
            cx d2  = cmul(dA1, dA1);
            cx d4  = cmul(d2, d2);
            cx d8  = cmul(d4, d4);
            cx d16 = cmul(d8, d8);
            cx d17 = cmul(d16, dA1);
            cx d34 = cmul(d17, d17);
            cx P = { 1.f, 0.f };
            if (seg & 1) P = cmul(P, d17);
            if (seg & 2) P = cmul(P, d34);
            const int j0 = 17 * seg;
            const int jend = (j0 + 17 < 65) ? (j0 + 17) : 65;
            for (int j = j0; j < jend; ++j) {
                if (role == 0) G_lds[j][2 * lane]     = (f16)( 2.f * (Cr * P.r - Ci * P.i));
                else {
                    G_lds[j][2 * lane + 1] = (f16)(-2.f * (Cr * P.i + Ci * P.r));
                    if (j == 64) { w_sh[lane][0] = P.r; w_sh[lane][1] = P.i; }
                }
                P = cmul(P, dA1);
            }

            // scan waves: build E-fragments in registers for n_f = 16*wave+frow
            // (index algebra HW-verified in round 9: absmax passed)
            if (wave < 4) {
                const int nf  = 16 * wave + frow;
                const int pnf = ph * N_ST + nf;
                float AreF = -expf(log_A_re[pnf]);
                float AimF = A_im[pnf];
                float mgF  = expf(dt * AreF);
                float phF  = dt * AimF;
                cx dAf = { mgF * cosf(phF), mgF * sinf(phF) };
                float invF = 1.0f / (AreF * AreF + AimF * AimF);
                float nrF  = dAf.r - 1.0f;
                float dBrF = (nrF * AreF + dAf.i * AimF) * invF;
                float dBiF = (dAf.i * AreF - nrF * AimF) * invF;
                cx f2  = cmul(dAf, dAf);
                cx f4  = cmul(f2, f2);
                cx f8  = cmul(f4, f4);
                cx f16p = cmul(f8, f8);
                cx f32p = cmul(f16p, f16p);
                cx one = { 1.f, 0.f };
                // frag0: col m = fk+q -> exponent 63-fk-q; walk q=7..0 from dA^(8*(7-fq))
                cx Pa = f32p;
                Pa = cmul(Pa, (fq < 2) ? f16p : one);
                Pa = cmul(Pa, ((fq & 1) == 0) ? f8 : one);
#pragma unroll
                for (int q = 7; q >= 0; --q) {
                    aRe0[q] = (f16)(Pa.r * dBrF - Pa.i * dBiF);
                    aIm0[q] = (f16)(Pa.r * dBiF + Pa.i * dBrF);
                    Pa = cmul(Pa, dAf);
                }
                // frag1: col m = 32+fk+q -> exponent 31-fk-q; start dA^(8*(3-fq))
                cx Pb = one;
                Pb = cmul(Pb, (fq < 2) ? f16p : one);
                Pb = cmul(Pb, ((fq & 1) == 0) ? f8 : one);
#pragma unroll
                for (int q = 7; q >= 0; --q) {
                    aRe1[q] = (f16)(Pb.r * dBrF - Pb.i * dBiF);
                    aIm1[q] = (f16)(Pb.r * dBiF + Pb.i * dBrF);
                    Pb = cmul(Pb, dAf);
                }
            }
        }
        barrier_lgkm();

        // ---- interval B: K[d] = G_ext[d] . dBv  (8 lanes per d, 512 thr) ----
        {
            const int t  = tid >> 3;
            const int l8 = tid & 7;
            f16x8 g0 = *(const f16x8*)&G_lds[t][l8 * 16];
            f16x8 g1 = *(const f16x8*)&G_lds[t][l8 * 16 + 8];
            f32x4 d0 = *(const f32x4*)&dBv_sh[l8 * 16];
            f32x4 d1 = *(const f32x4*)&dBv_sh[l8 * 16 + 4];
            f32x4 d2v = *(const f32x4*)&dBv_sh[l8 * 16 + 8];
            f32x4 d3 = *(const f32x4*)&dBv_sh[l8 * 16 + 12];
            float acc = 0.f;
#pragma unroll
            for (int k = 0; k < 4; ++k) {
                acc += (float)g0[k]     * d0[k];
                acc += (float)g0[k + 4] * d1[k];
                acc += (float)g1[k]     * d2v[k];
                acc += (float)g1[k + 4] * d3[k];
            }
            acc += __shfl_xor(acc, 1);
            acc += __shfl_xor(acc, 2);
            acc += __shfl_xor(acc, 4);
            if (l8 == 0) K_sh[t] = acc;
        }
        barrier_lgkm();

        // ---- interval C: Toeplitz expansion, D on diagonal ----
        for (int e = tid; e < 64 * 64; e += NTHR) {
            int i = e >> 6, jc = e & 63;
            A_lds[i][jc] = (jc < i) ? (f16)K_sh[i - jc]
                         : (jc == i ? (f16)(K_sh[0] + Dv) : (f16)0.f);
        }
        barrier_lgkm();

        // ---- fragment preload (out waves from LDS; scan w from w_sh) ----
        if (wave < 4) {
            const int m0 = 16 * wave;
#pragma unroll
            for (int p = 0; p < 4; ++p) {
                int n = m0 + fq * 4 + p;
                wr4[p] = w_sh[n][0]; wi4[p] = w_sh[n][1];
            }
        } else {
            const int mh = (wave - 4) & 1;
#pragma unroll
            for (int mt = 0; mt < 2; ++mt) {
                const int r0 = 32 * mh + 16 * mt + frow;
                aT0[mt] = *(const f16x8*)&A_lds[r0][fk];
                aT1[mt] = *(const f16x8*)&A_lds[r0][fk + 32];
#pragma unroll
                for (int k4 = 0; k4 < 4; ++k4)
                    aG[mt][k4] = *(const f16x8*)&G_lds[1 + r0][fk + 32 * k4];
            }
        }
        f16x4 yh[2][2];  // out: held y [jj][mt] (layers 0-2), static-indexed
        barrier_lgkm();  // preload reads done before main loop overwrites anything

        // ---- main pipelined group loop: ONE barrier per group-iteration ----
        for (int g = 0; g <= N_GROUPS + 1; ++g) {
            if (wave < 4) {                      // ---- scan ----
                if (g < N_GROUPS) {
                    const int gb = g & 1;
#pragma unroll
                    for (int j = 0; j < GSZ; ++j) {
                        f16x8 sf;
                        sf[0] = (f16)s_r[0]; sf[1] = (f16)s_i[0];
                        sf[2] = (f16)s_r[1]; sf[3] = (f16)s_i[1];
                        sf[4] = (f16)s_r[2]; sf[5] = (f16)s_i[2];
                        sf[6] = (f16)s_r[3]; sf[7] = (f16)s_i[3];
                        if (frow < 8)
                            *(f16x8*)&S_buf[gb][j][frow][32 * wave + fk] = sf;
                        const int co = (g * GSZ + j) * 64;
                        f16x8 b0 = *(const f16x8*)&U_all[fr8][co + fk];
                        f16x8 b1 = *(const f16x8*)&U_all[fr8][co + fk + 32];
                        f32x4 aR = {0.f,0.f,0.f,0.f}, aI = {0.f,0.f,0.f,0.f};
                        aR = __builtin_amdgcn_mfma_f32_16x16x32_f16(aRe0, b0, aR, 0, 0, 0);
                        aR = __builtin_amdgcn_mfma_f32_16x16x32_f16(aRe1, b1, aR, 0, 0, 0);
                        aI = __builtin_amdgcn_mfma_f32_16x16x32_f16(aIm0, b0, aI, 0, 0, 0);
                        aI = __builtin_amdgcn_mfma_f32_16x16x32_f16(aIm1, b1, aI, 0, 0, 0);
#pragma unroll
                        for (int p = 0; p < 4; ++p) {
                            float nr2 = wr4[p] * s_r[p] - wi4[p] * s_i[p] + aR[p];
                            float ni2 = wi4[p] * s_r[p] + wr4[p] * s_i[p] + aI[p];
                            s_r[p] = nr2; s_i[p] = ni2;
                        }
                    }
                }
            } else {                             // ---- out: (m-half mh, chunk-pair jcp) ----
                const int ow = wave - 4, mh = ow & 1, jcp = ow >> 1;
                if (layer < N_LAYERS - 1 && g >= 2 && frow < 8) {   // writeback group g-2
#pragma unroll
                    for (int jj = 0; jj < 2; ++jj) {
                        const int co2 = ((g - 2) * GSZ + jcp * 2 + jj) * 64;
                        *(f16x4*)&U_all[frow][co2 + 32 * mh + fq * 4]      = yh[jj][0];
                        *(f16x4*)&U_all[frow][co2 + 32 * mh + 16 + fq * 4] = yh[jj][1];
                    }
                }
                if (g >= 1 && g <= N_GROUPS) {           // compute group g-1
                    const int gp = g - 1, pb = gp & 1;
#pragma unroll
                    for (int jj = 0; jj < 2; ++jj) {
                        const int jc = jcp * 2 + jj;
                        const int co = (gp * GSZ + jc) * 64;
                        f16x8 b0 = *(const f16x8*)&U_all[fr8][co + fk];
                        f16x8 b1 = *(const f16x8*)&U_all[fr8][co + fk + 32];
                        f16x8 sv0 = *(const f16x8*)&S_buf[pb][jc][fr8][fk];
                        f16x8 sv1 = *(const f16x8*)&S_buf[pb][jc][fr8][fk + 32];
                        f16x8 sv2 = *(const f16x8*)&S_buf[pb][jc][fr8][fk + 64];
                        f16x8 sv3 = *(const f16x8*)&S_buf[pb][jc][fr8][fk + 96];
#pragma unroll
                        for (int mt = 0; mt < 2; ++mt) {
                            f32x4 acc = {0.f,0.f,0.f,0.f};
                            acc = __builtin_amdgcn_mfma_f32_16x16x32_f16(aT0[mt], b0, acc, 0, 0, 0);
                            acc = __builtin_amdgcn_mfma_f32_16x16x32_f16(aT1[mt], b1, acc, 0, 0, 0);
                            acc = __builtin_amdgcn_mfma_f32_16x16x32_f16(aG[mt][0], sv0, acc, 0, 0, 0);
                            acc = __builtin_amdgcn_mfma_f32_16x16x32_f16(aG[mt][1], sv1, acc, 0, 0, 0);
                            acc = __builtin_amdgcn_mfma_f32_16x16x32_f16(aG[mt][2], sv2, acc, 0, 0, 0);
                            acc = __builtin_amdgcn_mfma_f32_16x16x32_f16(aG[mt][3], sv3, acc, 0, 0, 0);
                            const int t0 = 32 * mh + 16 * mt + fq * 4;
                            f16x4 o;
#pragma unroll
                            for (int k = 0; k < 4; ++k) o[k] = (f16)acc[k];
                            if (layer == N_LAYERS - 1) {
                                if (frow < 8)
                                    *(f16x4*)&yb[(size_t)frow * L_SEQ + co + t0] = o;
                            } else {
                                yh[jj][mt] = o;
                            }
                        }
                    }
                }
            }
            barrier_lgkm();
        }

        // ---- final states from scan registers ----
        if (wave < 4 && frow < 8) {
#pragma unroll
            for (int p = 0; p < 4; ++p) {
                int n = 16 * wave + 4 * fq + p;
                size_t base = (((size_t)layer * B_SZ + bh * BH + frow) * H_SZ + h) * N_ST + n;
                st_re[base] = s_r[p];
                st_im[base] = s_i[p];
            }
        }
        __syncthreads();   // tables / U_all safe to overwrite for next layer
    }
}

// ---------- [H][B][L] f16 -> [L][B][H] f32 transpose ----------
__global__ __launch_bounds__(256, 4)
void hbl_to_lbh_kernel(const f16* __restrict__ in, float* __restrict__ out)
{
    __shared__ float t_sh[64][65];
    const int tid = threadIdx.x, bid = blockIdx.x;
    const int bb = bid & 15, lt = (bid >> 4) & 31, ht = bid >> 9;
    const int l0 = lt * 64, h0 = ht * 64;
#pragma unroll
    for (int i = 0; i < 4; ++i) {
        int idx = tid + i * 256;
        int hh = idx >> 4, l4 = (idx & 15) * 4;
        f16x4 v = *(const f16x4*)&in[((size_t)(h0 + hh) * B_SZ + bb) * L_SEQ + l0 + l4];
#pragma unroll
        for (int k = 0; k < 4; ++k) t_sh[hh][l4 + k] = (float)v[k];
    }
    __syncthreads();
#pragma unroll
    for (int i = 0; i < 4; ++i) {
        int idx = tid + i * 256;
        int ll = idx >> 4, h4 = (idx & 15) * 4;
        float4 o = make_float4(t_sh[h4][ll], t_sh[h4 + 1][ll],
                               t_sh[h4 + 2][ll], t_sh[h4 + 3][ll]);
        *(float4*)&out[((size_t)(l0 + ll) * B_SZ + bb) * H_SZ + h0 + h4] = o;
    }
}

extern "C" void kernel_launch(void* const* d_in, const int* in_sizes, int n_in,
                              void* d_out, int out_size, void* d_ws, size_t ws_size,
                              hipStream_t stream)
{
    const float* x        = (const float*)d_in[0];
    const float* enc_W    = (const float*)d_in[1];
    const float* enc_b    = (const float*)d_in[2];
    const float* log_dt   = (const float*)d_in[3];
    const float* log_A_re = (const float*)d_in[4];
    const float* A_im     = (const float*)d_in[5];
    const float* C_re     = (const float*)d_in[6];
    const float* C_im     = (const float*)d_in[7];
    const float* Dskip    = (const float*)d_in[8];

    float* out_lbh = (float*)d_out;                                  // [L,B,H]
    float* st_re   = out_lbh + (size_t)L_SEQ * B_SZ * H_SZ;
    float* st_im   = st_re + (size_t)N_LAYERS * B_SZ * H_SZ * N_ST;
    f16*   B0      = (f16*)d_ws;     // [H][B][L] f16 activations (32 MB)

    encoder_mfma_kernel<<<4096, 256, 0, stream>>>(x, enc_W, enc_b, B0);

    s4d_fused_kernel<<<1024, NTHR, 0, stream>>>(B0, log_dt, log_A_re, A_im,
                                                C_re, C_im, Dskip, st_re, st_im);

    hbl_to_lbh_kernel<<<4096, 256, 0, stream>>>(B0, out_lbh);        // final y -> [L,B,H]
}

// Round 13
// 232.732 us; speedup vs baseline: 3.7617x; 1.3702x over previous
//
#include <hip/hip_runtime.h>
#include <math.h>

#define L_SEQ 2048
#define B_SZ 16
#define DIN 64
#define H_SZ 512
#define N_ST 64
#define N_LAYERS 4
#define Q_CHUNK 64
#define N_CHUNKS (L_SEQ / Q_CHUNK)   // 32
#define GSZ 4                         // chunks per pipeline group (= 2 pairs)
#define N_GROUPS (N_CHUNKS / GSZ)     // 8
#define UPAD 2056                     // U_all row stride in f16 (16B-aligned)
#define NTHR 768                      // 12 waves: 8 scan + 4 out

typedef _Float16 f16;
typedef _Float16 f16x8 __attribute__((ext_vector_type(8)));
typedef _Float16 f16x4 __attribute__((ext_vector_type(4)));
typedef float    f32x4 __attribute__((ext_vector_type(4)));
typedef float    f32x16 __attribute__((ext_vector_type(16)));

struct cx { float r, i; };
__device__ __forceinline__ cx cmul(cx a, cx b) {
    return { a.r * b.r - a.i * b.i, a.r * b.i + a.i * b.r };
}

// LDS-only barrier (global loads/stores may stay in flight across it)
__device__ __forceinline__ void barrier_lgkm() {
    asm volatile("s_waitcnt lgkmcnt(0)\n\ts_barrier" ::: "memory");
}

// ---------- encoder (MFMA): out[h][b][l] = f16( sum_k x[l][b][k] W[k][h] + bias[h] ) ----------
__global__ __launch_bounds__(256, 4)
void encoder_mfma_kernel(const float* __restrict__ x, const float* __restrict__ W,
                         const float* __restrict__ bias, f16* __restrict__ out)
{
    __shared__ f16   x_sh[64][72];    // [l][k]
    __shared__ f16   w_t[64][72];     // [h][k]
    __shared__ float out_sh[64][68];
    __shared__ float b_sh[64];
    const int tid = threadIdx.x;
    const int bid = blockIdx.x;
    const int bb  = bid & 15;
    const int lt  = (bid >> 4) & 31;
    const int ht  = bid >> 9;
    const int l0 = lt * 64, h0 = ht * 64;

#pragma unroll
    for (int i = 0; i < 4; ++i) {
        int e  = tid + i * 256;            // 0..1023
        int r  = e >> 4;                   // 0..63 (l for x, k for W)
        int c4 = (e & 15) * 4;             // 0..60
        float4 xv = *(const float4*)&x[((size_t)(l0 + r) * B_SZ + bb) * DIN + c4];
        f16x4 xo; xo[0] = (f16)xv.x; xo[1] = (f16)xv.y; xo[2] = (f16)xv.z; xo[3] = (f16)xv.w;
        *(f16x4*)&x_sh[r][c4] = xo;        // [l][k]
        float4 wv = *(const float4*)&W[(size_t)r * H_SZ + h0 + c4];
        w_t[c4 + 0][r] = (f16)wv.x;        // [h][k] (transposed scatter)
        w_t[c4 + 1][r] = (f16)wv.y;
        w_t[c4 + 2][r] = (f16)wv.z;
        w_t[c4 + 3][r] = (f16)wv.w;
    }
    if (tid < 64) b_sh[tid] = bias[h0 + tid];
    __syncthreads();

    const int wave = tid >> 6;
    const int lane = tid & 63;
    const int frow = lane & 15;
    const int fk   = (lane >> 4) * 8;
    const int m0   = wave * 16;            // h strip per wave

    f16x8 a0 = *(const f16x8*)&w_t[m0 + frow][fk];
    f16x8 a1 = *(const f16x8*)&w_t[m0 + frow][fk + 32];
    float bv[4];
#pragma unroll
    for (int j = 0; j < 4; ++j) bv[j] = b_sh[m0 + (lane >> 4) * 4 + j];

#pragma unroll
    for (int nt = 0; nt < 4; ++nt) {       // l tiles
        f16x8 b0 = *(const f16x8*)&x_sh[nt * 16 + frow][fk];
        f16x8 b1 = *(const f16x8*)&x_sh[nt * 16 + frow][fk + 32];
        f32x4 acc = {0.f, 0.f, 0.f, 0.f};
        acc = __builtin_amdgcn_mfma_f32_16x16x32_f16(a0, b0, acc, 0, 0, 0);
        acc = __builtin_amdgcn_mfma_f32_16x16x32_f16(a1, b1, acc, 0, 0, 0);
#pragma unroll
        for (int j = 0; j < 4; ++j)
            out_sh[m0 + (lane >> 4) * 4 + j][nt * 16 + frow] = acc[j] + bv[j];
    }
    __syncthreads();

#pragma unroll
    for (int i = 0; i < 4; ++i) {
        int row = (tid >> 4) + i * 16;     // h row
        int c4  = (tid & 15) * 4;          // l col
        f32x4 v = *(const f32x4*)&out_sh[row][c4];
        f16x4 o;
#pragma unroll
        for (int k = 0; k < 4; ++k) o[k] = (f16)v[k];
        *(f16x4*)&out[((size_t)(h0 + row) * B_SZ + bb) * L_SEQ + l0 + c4] = o;
    }
}

// ---------- fused 4-layer S4D: one block per h, sequence LDS-resident ----------
// 12 waves = 8 scan + 4 out.
//   waves 0-7  ("scan"): wave w owns n in [8w, 8w+8) (E rows interleaved
//                        [2n+p][m], round-2 proven layout): per chunk publish
//                        S_pre -> S_buf, Z = E.U (2 MFMA 16x16x32), register
//                        scan of 2 complex pairs/lane.
//   waves 8-11 ("out"):  32x32x16 MFMA chunk-PAIRING: one MFMA covers
//                        16 batches x 2 chunks (cols 0-15 = chunk a, 16-31 =
//                        chunk b; A is chunk-invariant so no duplicate work).
//                        wave = (pair pp, row-tile mt): y = (T+D.I).U + G.S
//                        (4 + 8 MFMA per pair), group lag 1; writeback lag 2;
//                        global f16 store at layer 3.
// C/D map (m74/m101): col=lane&31, row=(reg&3)+8*(reg>>2)+4*(lane>>5).
// A/B map: row/col=lane&31, k=(lane>>5)*8+q.
__global__ __launch_bounds__(NTHR, 3)
void s4d_fused_kernel(f16* __restrict__ u_io,          // [H][B][L] f16: encoder out; final y in place
                      const float* __restrict__ log_dt, const float* __restrict__ log_A_re,
                      const float* __restrict__ A_im, const float* __restrict__ C_re,
                      const float* __restrict__ C_im, const float* __restrict__ Dskip,
                      float* __restrict__ st_re, float* __restrict__ st_im)
{
    __shared__ f16   A_lds[192][72];         // 0-63: Toeplitz(K)+D.I; 64-191: E interleaved [2n+p][m]
    __shared__ f16   G_lds[65][136];         // G_ext[j][n2], j=0..64
    __shared__ f16   U_all[16][UPAD];        // whole per-h sequence, f16, in place across layers
    __shared__ f16   S_buf[2][GSZ][16][136]; // S_pre per chunk of group [b][n2]
    __shared__ float dBv_sh[128];            // (dBr,dBi) interleaved per n
    __shared__ float K_sh[64];
    __shared__ float w_sh[64][2];            // dA^64 per n
    // total: 27648+17680+65792+34816+512+256+512 = 147216 B -> 1 block/CU

    const int tid  = threadIdx.x;
    const int wave = tid >> 6;
    const int lane = tid & 63;
    const int h    = blockIdx.x;
    const int frow = lane & 15;
    const int fq   = lane >> 4;
    const int fk   = fq * 8;
    const int r32  = lane & 31;              // 32x32 A-row / B-col
    const int kh   = (lane >> 5) * 8;        // 32x32 k-half offset
    const int ch   = (lane >> 4) & 1;        // 32x32 B-col chunk half
    const int thi  = (lane >> 5) * 4;        // 32x32 C/D row offset for hi lanes

    // ---- stage the whole layer-0 input sequence into LDS ----
    {
        const f16* ub = u_io + (size_t)h * B_SZ * L_SEQ;
        for (int u0 = tid; u0 < 16 * 256; u0 += NTHR) {
            int b = u0 >> 8, cidx = (u0 & 255) * 8;
            *(f16x8*)&U_all[b][cidx] = *(const f16x8*)&ub[(size_t)b * L_SEQ + cidx];
        }
    }
    f16* yb = u_io + (size_t)h * B_SZ * L_SEQ;   // final-layer f16 output (same h slot, safe)

    for (int layer = 0; layer < N_LAYERS; ++layer) {
        const int ph = layer * H_SZ + h;
        const int pn = ph * N_ST + lane;
        const float Dv = Dskip[ph];              // folded into Toeplitz diagonal

        // ---- table build: 12 waves = 4 roles x 3 power segments (round-7 proven,
        //      E-writes in round-2 interleaved form) ----
        {
            float dt   = expf(log_dt[ph]);
            float Are  = -expf(log_A_re[pn]);
            float Aim  = A_im[pn];
            float mg   = expf(dt * Are);
            float phs  = dt * Aim;
            cx dA1 = { mg * cosf(phs), mg * sinf(phs) };
            float invd = 1.0f / (Are * Are + Aim * Aim);
            float nr   = dA1.r - 1.0f;
            float dBr  = (nr * Are + dA1.i * Aim) * invd;
            float dBi  = (dA1.i * Are - nr * Aim) * invd;
            float Cr   = C_re[pn];
            float Ci   = C_im[pn];
            if (wave == 0) { dBv_sh[2 * lane] = dBr; dBv_sh[2 * lane + 1] = dBi; }

            const int role = wave & 3;     // 0:E_re 1:E_im 2:G_even 3:G_odd(+w)
            const int seg  = wave >> 2;    // 0,1,2
            cx dA2  = cmul(dA1, dA1);
            cx dA4  = cmul(dA2, dA2);
            cx dA8  = cmul(dA4, dA4);
            cx dA16 = cmul(dA8, dA8);
            cx P = { 1.f, 0.f };
            int j0 = 0, jend = 21;
            if (seg >= 1) { P = cmul(cmul(dA16, dA4), dA1); j0 = 21; jend = 42; }   // dA^21
            if (seg == 2) { P = cmul(P, P); j0 = 42; jend = (role >= 2) ? 65 : 64; } // dA^42
            for (int j = j0; j < jend; ++j) {
                if (role == 0)      A_lds[64 + 2 * lane][63 - j]     = (f16)(P.r * dBr - P.i * dBi);
                else if (role == 1) A_lds[64 + 2 * lane + 1][63 - j] = (f16)(P.r * dBi + P.i * dBr);
                else if (role == 2) G_lds[j][2 * lane]     = (f16)( 2.f * (Cr * P.r - Ci * P.i));
                else {
                    G_lds[j][2 * lane + 1] = (f16)(-2.f * (Cr * P.i + Ci * P.r));
                    if (j == 64) { w_sh[lane][0] = P.r; w_sh[lane][1] = P.i; }
                }
                P = cmul(P, dA1);
            }
        }
        barrier_lgkm();

        // ---- K[d] = G_ext[d] . dBv  (8 lanes per d) ----
        if (tid < 512) {
            const int t  = tid >> 3;
            const int l8 = tid & 7;
            f16x8 g0 = *(const f16x8*)&G_lds[t][l8 * 16];
            f16x8 g1 = *(const f16x8*)&G_lds[t][l8 * 16 + 8];
            f32x4 d0 = *(const f32x4*)&dBv_sh[l8 * 16];
            f32x4 d1 = *(const f32x4*)&dBv_sh[l8 * 16 + 4];
            f32x4 d2 = *(const f32x4*)&dBv_sh[l8 * 16 + 8];
            f32x4 d3 = *(const f32x4*)&dBv_sh[l8 * 16 + 12];
            float acc = 0.f;
#pragma unroll
            for (int k = 0; k < 4; ++k) {
                acc += (float)g0[k]     * d0[k];
                acc += (float)g0[k + 4] * d1[k];
                acc += (float)g1[k]     * d2[k];
                acc += (float)g1[k + 4] * d3[k];
            }
            acc += __shfl_xor(acc, 1);
            acc += __shfl_xor(acc, 2);
            acc += __shfl_xor(acc, 4);
            if (l8 == 0) K_sh[t] = acc;
        }
        barrier_lgkm();
        for (int e = tid; e < 64 * 64; e += NTHR) {   // Toeplitz expansion, D on diagonal
            int i = e >> 6, jc = e & 63;
            A_lds[i][jc] = (jc < i) ? (f16)K_sh[i - jc]
                         : (jc == i ? (f16)(K_sh[0] + Dv) : (f16)0.f);
        }
        barrier_lgkm();

        // ---- per-role chunk-invariant fragments / constants ----
        f16x8 aE0, aE1;                          // scan (round-2 layout)
        f16x8 aT[4], aG[8];                      // out (32x32 A-frags)
        float war = 0.f, wai = 0.f, wbr = 0.f, wbi = 0.f;
        float s0r = 0.f, s0i = 0.f, s1r = 0.f, s1i = 0.f;
        if (wave < 8) {
            aE0 = *(const f16x8*)&A_lds[64 + 16 * wave + frow][fk];
            aE1 = *(const f16x8*)&A_lds[64 + 16 * wave + frow][fk + 32];
            const int n0 = 8 * wave + 2 * fq;
            war = w_sh[n0][0];     wai = w_sh[n0][1];
            wbr = w_sh[n0 + 1][0]; wbi = w_sh[n0 + 1][1];
        } else {
            const int mt = (wave - 8) & 1;
#pragma unroll
            for (int ks = 0; ks < 4; ++ks)
                aT[ks] = *(const f16x8*)&A_lds[32 * mt + r32][ks * 16 + kh];
#pragma unroll
            for (int ks = 0; ks < 8; ++ks)
                aG[ks] = *(const f16x8*)&G_lds[1 + 32 * mt + r32][ks * 16 + kh];
        }
        f16x4 yh[4];   // out: held y (layers 0-2), set at g>=1 before first use at g>=2

        // ---- main pipelined group loop: ONE barrier per group-iteration ----
        for (int g = 0; g <= N_GROUPS + 1; ++g) {
            if (wave < 8) {                      // ---- scan (round-2 proven body) ----
                if (g < N_GROUPS) {
                    const int gb = g & 1;
#pragma unroll
                    for (int j = 0; j < GSZ; ++j) {
                        f16x4 sf; sf[0] = (f16)s0r; sf[1] = (f16)s0i;
                        sf[2] = (f16)s1r; sf[3] = (f16)s1i;
                        *(f16x4*)&S_buf[gb][j][frow][16 * wave + fq * 4] = sf;
                        const int co = (g * GSZ + j) * 64;
                        f16x8 b0 = *(const f16x8*)&U_all[frow][co + fk];
                        f16x8 b1 = *(const f16x8*)&U_all[frow][co + fk + 32];
                        f32x4 acc = {0.f, 0.f, 0.f, 0.f};
                        acc = __builtin_amdgcn_mfma_f32_16x16x32_f16(aE0, b0, acc, 0, 0, 0);
                        acc = __builtin_amdgcn_mfma_f32_16x16x32_f16(aE1, b1, acc, 0, 0, 0);
                        float t0r = war * s0r - wai * s0i + acc[0];
                        float t0i = wai * s0r + war * s0i + acc[1];
                        float t1r = wbr * s1r - wbi * s1i + acc[2];
                        float t1i = wbi * s1r + wbr * s1i + acc[3];
                        s0r = t0r; s0i = t0i; s1r = t1r; s1i = t1i;
                    }
                }
            } else {                             // ---- out: (pair pp, row-tile mt) ----
                const int ow = wave - 8, pp = ow >> 1, mt = ow & 1;
                if (layer < N_LAYERS - 1 && g >= 2) {    // writeback pair pp of group g-2
                    const int co2 = ((g - 2) * GSZ + pp * 2 + ch) * 64 + 32 * mt;
#pragma unroll
                    for (int q = 0; q < 4; ++q)
                        *(f16x4*)&U_all[frow][co2 + 8 * q + thi] = yh[q];
                }
                if (g >= 1 && g <= N_GROUPS) {           // compute pair pp of group g-1
                    const int gp = g - 1, pb = gp & 1;
                    const int jc = pp * 2 + ch;          // this lane's chunk of the pair
                    const int co = (gp * GSZ + jc) * 64;
                    f16x8 bT[4], bG[8];
#pragma unroll
                    for (int ks = 0; ks < 4; ++ks)
                        bT[ks] = *(const f16x8*)&U_all[frow][co + ks * 16 + kh];
#pragma unroll
                    for (int ks = 0; ks < 8; ++ks)
                        bG[ks] = *(const f16x8*)&S_buf[pb][jc][frow][ks * 16 + kh];
                    f32x16 acc = {0.f,0.f,0.f,0.f,0.f,0.f,0.f,0.f,
                                  0.f,0.f,0.f,0.f,0.f,0.f,0.f,0.f};
#pragma unroll
                    for (int ks = 0; ks < 4; ++ks)
                        acc = __builtin_amdgcn_mfma_f32_32x32x16_f16(aT[ks], bT[ks], acc, 0, 0, 0);
#pragma unroll
                    for (int ks = 0; ks < 8; ++ks)
                        acc = __builtin_amdgcn_mfma_f32_32x32x16_f16(aG[ks], bG[ks], acc, 0, 0, 0);
                    // C/D: reg r=4q+k -> t_local = k + 8q + thi; t = 32*mt + t_local
                    if (layer == N_LAYERS - 1) {
#pragma unroll
                        for (int q = 0; q < 4; ++q) {
                            f16x4 o;
#pragma unroll
                            for (int k = 0; k < 4; ++k) o[k] = (f16)acc[4 * q + k];
                            *(f16x4*)&yb[(size_t)frow * L_SEQ + co + 32 * mt + 8 * q + thi] = o;
                        }
                    } else {
#pragma unroll
                        for (int q = 0; q < 4; ++q) {
                            f16x4 o;
#pragma unroll
                            for (int k = 0; k < 4; ++k) o[k] = (f16)acc[4 * q + k];
                            yh[q] = o;
                        }
                    }
                }
            }
            barrier_lgkm();
        }

        // ---- final states from scan registers ----
        if (wave < 8) {
            const int na = wave * 8 + fq * 2;
            const size_t base = (((size_t)layer * B_SZ + frow) * H_SZ + h) * N_ST + na;
            st_re[base]     = s0r; st_im[base]     = s0i;
            st_re[base + 1] = s1r; st_im[base + 1] = s1i;
        }
        __syncthreads();   // tables / U_all safe to overwrite for next layer
    }
}

// ---------- [H][B][L] f16 -> [L][B][H] f32 transpose ----------
__global__ __launch_bounds__(256, 4)
void hbl_to_lbh_kernel(const f16* __restrict__ in, float* __restrict__ out)
{
    __shared__ float t_sh[64][65];
    const int tid = threadIdx.x, bid = blockIdx.x;
    const int bb = bid & 15, lt = (bid >> 4) & 31, ht = bid >> 9;
    const int l0 = lt * 64, h0 = ht * 64;
#pragma unroll
    for (int i = 0; i < 4; ++i) {
        int idx = tid + i * 256;
        int hh = idx >> 4, l4 = (idx & 15) * 4;
        f16x4 v = *(const f16x4*)&in[((size_t)(h0 + hh) * B_SZ + bb) * L_SEQ + l0 + l4];
#pragma unroll
        for (int k = 0; k < 4; ++k) t_sh[hh][l4 + k] = (float)v[k];
    }
    __syncthreads();
#pragma unroll
    for (int i = 0; i < 4; ++i) {
        int idx = tid + i * 256;
        int ll = idx >> 4, h4 = (idx & 15) * 4;
        float4 o = make_float4(t_sh[h4][ll], t_sh[h4 + 1][ll],
                               t_sh[h4 + 2][ll], t_sh[h4 + 3][ll]);
        *(float4*)&out[((size_t)(l0 + ll) * B_SZ + bb) * H_SZ + h0 + h4] = o;
    }
}

extern "C" void kernel_launch(void* const* d_in, const int* in_sizes, int n_in,
                              void* d_out, int out_size, void* d_ws, size_t ws_size,
                              hipStream_t stream)
{
    const float* x        = (const float*)d_in[0];
    const float* enc_W    = (const float*)d_in[1];
    const float* enc_b    = (const float*)d_in[2];
    const float* log_dt   = (const float*)d_in[3];
    const float* log_A_re = (const float*)d_in[4];
    const float* A_im     = (const float*)d_in[5];
    const float* C_re     = (const float*)d_in[6];
    const float* C_im     = (const float*)d_in[7];
    const float* Dskip    = (const float*)d_in[8];

    float* out_lbh = (float*)d_out;                                  // [L,B,H]
    float* st_re   = out_lbh + (size_t)L_SEQ * B_SZ * H_SZ;
    float* st_im   = st_re + (size_t)N_LAYERS * B_SZ * H_SZ * N_ST;
    f16*   B0      = (f16*)d_ws;     // [H][B][L] f16 activations (32 MB)

    encoder_mfma_kernel<<<4096, 256, 0, stream>>>(x, enc_W, enc_b, B0);

    s4d_fused_kernel<<<512, NTHR, 0, stream>>>(B0, log_dt, log_A_re, A_im,
                                               C_re, C_im, Dskip, st_re, st_im);

    hbl_to_lbh_kernel<<<4096, 256, 0, stream>>>(B0, out_lbh);        // final y -> [L,B,H]
}